// Round 2
// baseline (611.482 us; speedup 1.0000x reference)
//
#include <hip/hip_runtime.h>

typedef __attribute__((ext_vector_type(4))) float f32x4;
typedef __attribute__((ext_vector_type(8))) short s16x8;  // 8 x bf16 fragment

#define DEVI static __device__ __forceinline__

constexpr int BB = 4, HH = 8, TT = 2048, DD = 256;

// fp32 -> bf16 round-to-nearest-even
DEVI short f2bf(float f) {
  union { float f; unsigned u; } x; x.f = f;
  unsigned r = x.u + 0x7fffu + ((x.u >> 16) & 1u);
  return (short)(r >> 16);
}

// async global->LDS, 16B per lane; LDS dest = wave-uniform base + lane*16
DEVI void gl16(const short* g, short* l) {
  __builtin_amdgcn_global_load_lds(
      (const __attribute__((address_space(1))) void*)g,
      (__attribute__((address_space(3))) void*)l, 16, 0, 0);
}

// ---------------------------------------------------------------------------
// Kernel 1: cast r' -> rbf, Q -> Qt (transposed, bf16), E -> Ebf
// ---------------------------------------------------------------------------
__global__ void cast_prep(const float* __restrict__ r, const float* __restrict__ Q,
                          const float* __restrict__ E,
                          short* __restrict__ rbf, short* __restrict__ Qt,
                          short* __restrict__ Ebf) {
  int idx = blockIdx.x * blockDim.x + threadIdx.x;
  int stride = gridDim.x * blockDim.x;
  for (int i = idx; i < BB * TT * DD; i += stride) rbf[i] = f2bf(r[i]);
  for (int i = idx; i < HH * DD * DD; i += stride) {
    int h = i / (DD * DD), rem = i % (DD * DD), j = rem / DD, i2 = rem % DD;
    Qt[i] = f2bf(Q[(h * DD + i2) * DD + j]);  // Qt[h][j][i2] = Q[h][i2][j]
    Ebf[i] = f2bf(E[i]);
  }
}

// ---------------------------------------------------------------------------
// Kernel 2: C[M][N] = X[M][K=256] @ W[N][K]^T  (bf16 in, fp32 acc, bf16 out)
// mode 0: X=rbf[b] (M=2048), W=Qt[h] (N=256)  -> Abf[b][h][t][j]
// mode 1: X=Ebf[h] (M=256),  W=rbf[b] (N=2048) -> Vt[b][h][i][u]
// Epilogue: LDS-transpose staging -> 16B coalesced stores.
// ---------------------------------------------------------------------------
__global__ __launch_bounds__(256, 2)
void prep_gemm(const short* __restrict__ rbf, const short* __restrict__ Qt,
               const short* __restrict__ Ebf, short* __restrict__ Abf,
               short* __restrict__ Vtbf, int mode) {
  __shared__ __align__(16) short w_lds[64 * 256];
  int tid = threadIdx.x, lane = tid & 63, wid = tid >> 6;
  int h = blockIdx.y, b = blockIdx.z, bx = blockIdx.x;
  const short* X; const short* W; short* C; int ldC, m0, n0;
  if (mode == 0) {
    m0 = (bx >> 2) * 64; n0 = (bx & 3) * 64;
    X = rbf + (size_t)b * TT * DD;
    W = Qt + (size_t)h * DD * DD;
    C = Abf + (size_t)(b * HH + h) * TT * DD; ldC = DD;
  } else {
    m0 = (bx & 3) * 64; n0 = (bx >> 2) * 64;
    X = Ebf + (size_t)h * DD * DD;
    W = rbf + (size_t)b * TT * DD;
    C = Vtbf + (size_t)(b * HH + h) * DD * TT; ldC = TT;
  }
  // stage W rows n0..n0+63, XOR-swizzled in 16B blocks: blk' = blk ^ (row&7)
  #pragma unroll
  for (int it = 0; it < 8; ++it) {
    int t = it * 256 + tid;
    int row = t >> 5, kb = t & 31;
    s16x8 v = *(const s16x8*)(W + (size_t)(n0 + row) * DD + kb * 8);
    *(s16x8*)(&w_lds[row * 256 + ((kb ^ (row & 7)) << 3)]) = v;
  }
  // X fragments (A operand): row = m0+wid*16+(lane&15), k = ks*32+(lane>>4)*8+e
  s16x8 a[8];
  {
    const short* xrow = X + (size_t)(m0 + wid * 16 + (lane & 15)) * DD + (lane >> 4) * 8;
    #pragma unroll
    for (int ks = 0; ks < 8; ++ks) a[ks] = *(const s16x8*)(xrow + ks * 32);
  }
  __syncthreads();
  f32x4 c[4] = {};
  #pragma unroll
  for (int n = 0; n < 4; ++n) {
    int row = n * 16 + (lane & 15);
    #pragma unroll
    for (int ks = 0; ks < 8; ++ks) {
      int kb = ks * 4 + (lane >> 4);
      s16x8 bfr = *(const s16x8*)(&w_lds[row * 256 + ((kb ^ (row & 7)) << 3)]);
      c[n] = __builtin_amdgcn_mfma_f32_16x16x32_bf16(a[ks], bfr, c[n], 0, 0, 0);
    }
  }
  // Stage C tile (64x64 bf16) into LDS (swizzled), then coalesced 16B stores.
  __syncthreads();
  #pragma unroll
  for (int n = 0; n < 4; ++n) {
    int col = n * 16 + (lane & 15);
    int cb = col >> 3;
    #pragma unroll
    for (int rr = 0; rr < 4; ++rr) {
      int row = wid * 16 + (lane >> 4) * 4 + rr;
      w_lds[row * 64 + ((cb ^ (row & 7)) << 3) + (col & 7)] = f2bf(c[n][rr]);
    }
  }
  __syncthreads();
  #pragma unroll
  for (int q = 0; q < 2; ++q) {
    int t = q * 256 + tid;
    int row = t >> 3, cb = t & 7;
    s16x8 v = *(const s16x8*)(&w_lds[row * 64 + ((cb ^ (row & 7)) << 3)]);
    *(s16x8*)(&C[(size_t)(m0 + row) * ldC + n0 + cb * 8]) = v;
  }
}

// ---------------------------------------------------------------------------
// Kernel 3: causal main loop. Block = (pair p, u-parity), handles t-tiles
// {p, 15-p} of 128 rows each -> uniform 17 u-tiles per block.
// 4 waves x 32 t-rows/wave; B-frags reused across the 2 row-blocks.
// K/V staged via global_load_lds with pre-swizzled source.
// ---------------------------------------------------------------------------
__global__ __launch_bounds__(256, 2)
void attn_main(const short* __restrict__ Abf, const short* __restrict__ Kbf,
               const short* __restrict__ Vtb, float* __restrict__ out) {
  __shared__ __align__(16) short k_lds[64 * 256];   // 32KB [u_loc][j swz]
  __shared__ __align__(16) short v_lds[256 * 64];   // 32KB [i][u_loc swz]
  __shared__ __align__(16) short s_lds[128 * 32];   //  8KB [t_loc][k_loc swz]
  int tid = threadIdx.x, lane = tid & 63, wid = tid >> 6;
  int pp = blockIdx.x;            // 0..15
  int p = pp >> 1, par = pp & 1;
  int h = blockIdx.y, b = blockIdx.z;

  const short* Ab0 = Abf + (size_t)(b * HH + h) * TT * DD;
  const short* Kb = Kbf + (size_t)b * TT * DD;
  const short* Vb = Vtb + (size_t)(b * HH + h) * DD * TT;

  #pragma unroll 1
  for (int hv = 0; hv < 2; ++hv) {
    int tt = hv ? (15 - p) : p;
    // A fragments: 2 row-blocks x 8 k-steps (64 VGPRs), held for the t-tile
    s16x8 a[2][8];
    {
      const short* abase = Ab0 + (size_t)(tt * 128 + wid * 32 + (lane & 15)) * DD + ((lane >> 4) << 3);
      #pragma unroll
      for (int rb = 0; rb < 2; ++rb)
        #pragma unroll
        for (int ks = 0; ks < 8; ++ks)
          a[rb][ks] = *(const s16x8*)(abase + rb * 16 * DD + ks * 32);
    }
    f32x4 acc[2][16] = {};
    int nU = 2 * tt + 2;
    #pragma unroll 1
    for (int iu = par; iu < nU; iu += 2) {
      int U = iu * 64;
      __syncthreads();   // previous tile's readers done; LDS reusable
      {
        // K tile: 64 rows x 256 shorts; 32 chunks of 1KB, 8 per wave
        const short* ksrc = Kb + (size_t)U * DD;
        #pragma unroll
        for (int c = 0; c < 8; ++c) {
          int kc = wid * 8 + c;
          int row = kc * 2 + (lane >> 5);
          int blk = lane & 31;
          gl16(ksrc + (size_t)row * DD + ((blk ^ (row & 7)) << 3), &k_lds[kc * 512]);
        }
        // V tile: 256 rows x 64 shorts; 32 chunks of 1KB, 8 per wave
        #pragma unroll
        for (int c = 0; c < 8; ++c) {
          int vc = wid * 8 + c;
          int row = vc * 8 + (lane >> 3);
          int cb = lane & 7;
          gl16(Vb + (size_t)row * TT + U + ((cb ^ (row & 7)) << 3), &v_lds[vc * 512]);
        }
      }
      __syncthreads();   // drains vmcnt(0): tiles visible to all waves

      #pragma unroll
      for (int hh = 0; hh < 2; ++hh) {
        // S = A @ K^T for u-half hh (32 u cols), both row-blocks
        f32x4 s[2][2] = {{{0,0,0,0},{0,0,0,0}},{{0,0,0,0},{0,0,0,0}}};
        #pragma unroll
        for (int n2 = 0; n2 < 2; ++n2) {
          int row = (hh * 2 + n2) * 16 + (lane & 15);
          #pragma unroll
          for (int ks = 0; ks < 8; ++ks) {
            int kb = ks * 4 + (lane >> 4);
            s16x8 bfr = *(const s16x8*)(&k_lds[row * 256 + ((kb ^ (row & 7)) << 3)]);
            s[0][n2] = __builtin_amdgcn_mfma_f32_16x16x32_bf16(a[0][ks], bfr, s[0][n2], 0, 0, 0);
            s[1][n2] = __builtin_amdgcn_mfma_f32_16x16x32_bf16(a[1][ks], bfr, s[1][n2], 0, 0, 0);
          }
        }
        // causal mask + bf16 + write to per-wave s_lds region (swizzled)
        #pragma unroll
        for (int rb = 0; rb < 2; ++rb) {
          #pragma unroll
          for (int n2 = 0; n2 < 2; ++n2) {
            #pragma unroll
            for (int rr = 0; rr < 4; ++rr) {
              int t_loc = wid * 32 + rb * 16 + (lane >> 4) * 4 + rr;
              int u_glob = U + (hh * 2 + n2) * 16 + (lane & 15);
              float v = (u_glob <= tt * 128 + t_loc) ? s[rb][n2][rr] : 0.0f;
              int kloc = n2 * 16 + (lane & 15);
              int cb = kloc >> 3;
              s_lds[t_loc * 32 + ((cb ^ ((t_loc >> 1) & 3)) << 3) + (kloc & 7)] = f2bf(v);
            }
          }
        }
        // PV for this u-half (k=32): af read once per row-block, bv reused x2
        s16x8 af[2];
        #pragma unroll
        for (int rb = 0; rb < 2; ++rb) {
          int R = wid * 32 + rb * 16 + (lane & 15);
          int cb2 = (lane >> 4) ^ ((R >> 1) & 3);
          af[rb] = *(const s16x8*)(&s_lds[R * 32 + (cb2 << 3)]);
        }
        #pragma unroll
        for (int ni = 0; ni < 16; ++ni) {
          int vrow = ni * 16 + (lane & 15);
          int ub = hh * 4 + (lane >> 4);
          s16x8 bv = *(const s16x8*)(&v_lds[vrow * 64 + ((ub ^ (vrow & 7)) << 3)]);
          acc[0][ni] = __builtin_amdgcn_mfma_f32_16x16x32_bf16(af[0], bv, acc[0][ni], 0, 0, 0);
          acc[1][ni] = __builtin_amdgcn_mfma_f32_16x16x32_bf16(af[1], bv, acc[1][ni], 0, 0, 0);
        }
      }
    }
    // epilogue: head-sum via atomics
    float* ob = out + ((size_t)b * TT + tt * 128 + wid * 32) * DD;
    #pragma unroll
    for (int rb = 0; rb < 2; ++rb) {
      #pragma unroll
      for (int ni = 0; ni < 16; ++ni) {
        int col = ni * 16 + (lane & 15);
        #pragma unroll
        for (int rr = 0; rr < 4; ++rr) {
          int row = rb * 16 + (lane >> 4) * 4 + rr;
          atomicAdd(&ob[row * DD + col], acc[rb][ni][rr]);
        }
      }
    }
  }
}

// ---------------------------------------------------------------------------
extern "C" void kernel_launch(void* const* d_in, const int* in_sizes, int n_in,
                              void* d_out, int out_size, void* d_ws, size_t ws_size,
                              hipStream_t stream) {
  const float* r = (const float*)d_in[0];
  const float* Q = (const float*)d_in[1];
  const float* E = (const float*)d_in[2];
  float* out = (float*)d_out;
  char* ws = (char*)d_ws;

  size_t off = 0;
  short* rbf = (short*)(ws + off); off += (size_t)BB * TT * DD * 2;      // 4 MiB
  short* Qt  = (short*)(ws + off); off += (size_t)HH * DD * DD * 2;      // 1 MiB
  short* Ebf = (short*)(ws + off); off += (size_t)HH * DD * DD * 2;      // 1 MiB
  short* Abf = (short*)(ws + off); off += (size_t)BB * HH * TT * DD * 2; // 32 MiB
  short* Vtb = (short*)(ws + off); off += (size_t)BB * HH * DD * TT * 2; // 32 MiB

  hipMemsetAsync(d_out, 0, (size_t)out_size * sizeof(float), stream);
  cast_prep<<<1024, 256, 0, stream>>>(r, Q, E, rbf, Qt, Ebf);
  prep_gemm<<<dim3(128, HH, BB), 256, 0, stream>>>(rbf, Qt, Ebf, Abf, Vtb, 0);
  prep_gemm<<<dim3(128, HH, BB), 256, 0, stream>>>(rbf, Qt, Ebf, Abf, Vtb, 1);
  attn_main<<<dim3(16, HH, BB), 256, 0, stream>>>(Abf, rbf, Vtb, out);
}

// Round 3
// 229.035 us; speedup vs baseline: 2.6698x; 2.6698x over previous
//
#include <hip/hip_runtime.h>

typedef __attribute__((ext_vector_type(4))) float f32x4;
typedef __attribute__((ext_vector_type(8))) short s16x8;  // 8 x bf16 fragment

#define DEVI static __device__ __forceinline__

constexpr int BB = 4, HH = 8, TT = 2048, DD = 256;

// fp32 -> bf16 round-to-nearest-even
DEVI short f2bf(float f) {
  union { float f; unsigned u; } x; x.f = f;
  unsigned r = x.u + 0x7fffu + ((x.u >> 16) & 1u);
  return (short)(r >> 16);
}

// async global->LDS, 16B per lane; LDS dest = wave-uniform base + lane*16
DEVI void gl16(const short* g, short* l) {
  __builtin_amdgcn_global_load_lds(
      (const __attribute__((address_space(1))) void*)g,
      (__attribute__((address_space(3))) void*)l, 16, 0, 0);
}

// ---------------------------------------------------------------------------
// Kernel 1: cast r' -> rbf, Q -> Qt (transposed, bf16), E -> Ebf
// ---------------------------------------------------------------------------
__global__ void cast_prep(const float* __restrict__ r, const float* __restrict__ Q,
                          const float* __restrict__ E,
                          short* __restrict__ rbf, short* __restrict__ Qt,
                          short* __restrict__ Ebf) {
  int idx = blockIdx.x * blockDim.x + threadIdx.x;
  int stride = gridDim.x * blockDim.x;
  for (int i = idx; i < BB * TT * DD; i += stride) rbf[i] = f2bf(r[i]);
  for (int i = idx; i < HH * DD * DD; i += stride) {
    int h = i / (DD * DD), rem = i % (DD * DD), j = rem / DD, i2 = rem % DD;
    Qt[i] = f2bf(Q[(h * DD + i2) * DD + j]);  // Qt[h][j][i2] = Q[h][i2][j]
    Ebf[i] = f2bf(E[i]);
  }
}

// ---------------------------------------------------------------------------
// Kernel 2: C[M][N] = X[M][K=256] @ W[N][K]^T  (bf16 in, fp32 acc, bf16 out)
// mode 0: X=rbf[b] (M=2048), W=Qt[h] (N=256)  -> Abf[b][h][t][j]
// mode 1: X=Ebf[h] (M=256),  W=rbf[b] (N=2048) -> Vt[b][h][i][u]
// ---------------------------------------------------------------------------
__global__ __launch_bounds__(256, 2)
void prep_gemm(const short* __restrict__ rbf, const short* __restrict__ Qt,
               const short* __restrict__ Ebf, short* __restrict__ Abf,
               short* __restrict__ Vtbf, int mode) {
  __shared__ __align__(16) short w_lds[64 * 256];
  int tid = threadIdx.x, lane = tid & 63, wid = tid >> 6;
  int h = blockIdx.y, b = blockIdx.z, bx = blockIdx.x;
  const short* X; const short* W; short* C; int ldC, m0, n0;
  if (mode == 0) {
    m0 = (bx >> 2) * 64; n0 = (bx & 3) * 64;
    X = rbf + (size_t)b * TT * DD;
    W = Qt + (size_t)h * DD * DD;
    C = Abf + (size_t)(b * HH + h) * TT * DD; ldC = DD;
  } else {
    m0 = (bx & 3) * 64; n0 = (bx >> 2) * 64;
    X = Ebf + (size_t)h * DD * DD;
    W = rbf + (size_t)b * TT * DD;
    C = Vtbf + (size_t)(b * HH + h) * DD * TT; ldC = TT;
  }
  #pragma unroll
  for (int it = 0; it < 8; ++it) {
    int t = it * 256 + tid;
    int row = t >> 5, kb = t & 31;
    s16x8 v = *(const s16x8*)(W + (size_t)(n0 + row) * DD + kb * 8);
    *(s16x8*)(&w_lds[row * 256 + ((kb ^ (row & 7)) << 3)]) = v;
  }
  s16x8 a[8];
  {
    const short* xrow = X + (size_t)(m0 + wid * 16 + (lane & 15)) * DD + (lane >> 4) * 8;
    #pragma unroll
    for (int ks = 0; ks < 8; ++ks) a[ks] = *(const s16x8*)(xrow + ks * 32);
  }
  __syncthreads();
  f32x4 c[4] = {};
  #pragma unroll
  for (int n = 0; n < 4; ++n) {
    int row = n * 16 + (lane & 15);
    #pragma unroll
    for (int ks = 0; ks < 8; ++ks) {
      int kb = ks * 4 + (lane >> 4);
      s16x8 bfr = *(const s16x8*)(&w_lds[row * 256 + ((kb ^ (row & 7)) << 3)]);
      c[n] = __builtin_amdgcn_mfma_f32_16x16x32_bf16(a[ks], bfr, c[n], 0, 0, 0);
    }
  }
  __syncthreads();
  #pragma unroll
  for (int n = 0; n < 4; ++n) {
    int col = n * 16 + (lane & 15);
    int cb = col >> 3;
    #pragma unroll
    for (int rr = 0; rr < 4; ++rr) {
      int row = wid * 16 + (lane >> 4) * 4 + rr;
      w_lds[row * 64 + ((cb ^ (row & 7)) << 3) + (col & 7)] = f2bf(c[n][rr]);
    }
  }
  __syncthreads();
  #pragma unroll
  for (int q = 0; q < 2; ++q) {
    int t = q * 256 + tid;
    int row = t >> 3, cb = t & 7;
    s16x8 v = *(const s16x8*)(&w_lds[row * 64 + ((cb ^ (row & 7)) << 3)]);
    *(s16x8*)(&C[(size_t)(m0 + row) * ldC + n0 + cb * 8]) = v;
  }
}

// ---------------------------------------------------------------------------
// Kernel 3: causal main loop. Block q: p = q>>5 in [0,8), (h,b) = q&31.
// Handles t-tiles p then 15-p (128 rows each), u ascending -> uniform 34
// u-tile units/block, concurrent same-u sweeps for L2/L3 reuse, and the 8
// pair-blocks sharing V[b][h] have equal (q mod 8) -> same XCD (round-robin).
// Double-buffered global_load_lds staging, counted vmcnt, raw barriers.
// ---------------------------------------------------------------------------
__global__ __launch_bounds__(256, 1)
void attn_main(const short* __restrict__ Abf, const short* __restrict__ Kbf,
               const short* __restrict__ Vtb, float* __restrict__ out) {
  __shared__ __align__(16) short k_lds[2][64 * 256];   // 2 x 32KB [u_loc][j swz]
  __shared__ __align__(16) short v_lds[2][256 * 64];   // 2 x 32KB [i][u_loc swz]
  __shared__ __align__(16) short s_lds[128 * 32];      // 8KB [t_loc][k_loc swz]
  int tid = threadIdx.x, lane = tid & 63, wid = tid >> 6;
  int q = blockIdx.x;
  int p = q >> 5, hb = q & 31;
  int h = hb & 7, b = hb >> 3;

  const short* Ab0 = Abf + (size_t)(b * HH + h) * TT * DD;
  const short* Kb = Kbf + (size_t)b * TT * DD;
  const short* Vb = Vtb + (size_t)(b * HH + h) * DD * TT;

#define STAGE(bufi, iu_) do {                                                  \
    int U_ = (iu_) * 64;                                                       \
    const short* ksrc_ = Kb + (size_t)U_ * DD;                                 \
    _Pragma("unroll")                                                          \
    for (int c_ = 0; c_ < 8; ++c_) {                                           \
      int kc_ = wid * 8 + c_;                                                  \
      int row_ = kc_ * 2 + (lane >> 5);                                        \
      int blk_ = lane & 31;                                                    \
      gl16(ksrc_ + (size_t)row_ * DD + ((blk_ ^ (row_ & 7)) << 3),             \
           &k_lds[bufi][kc_ * 512]);                                           \
    }                                                                          \
    _Pragma("unroll")                                                          \
    for (int c_ = 0; c_ < 8; ++c_) {                                           \
      int vc_ = wid * 8 + c_;                                                  \
      int row_ = vc_ * 8 + (lane >> 3);                                        \
      int cb_ = lane & 7;                                                      \
      gl16(Vb + (size_t)row_ * TT + U_ + ((cb_ ^ (row_ & 7)) << 3),            \
           &v_lds[bufi][vc_ * 512]);                                           \
    }                                                                          \
  } while (0)

  #pragma unroll 1
  for (int hv = 0; hv < 2; ++hv) {
    int tt = hv ? (15 - p) : p;
    // A fragments: 2 row-blocks x 8 k-steps, held for the whole t-tile
    s16x8 a[2][8];
    {
      const short* abase = Ab0 + (size_t)(tt * 128 + wid * 32 + (lane & 15)) * DD + ((lane >> 4) << 3);
      #pragma unroll
      for (int rb = 0; rb < 2; ++rb)
        #pragma unroll
        for (int ks = 0; ks < 8; ++ks)
          a[rb][ks] = *(const s16x8*)(abase + rb * 16 * DD + ks * 32);
    }
    f32x4 acc[2][16] = {};
    int nU = 2 * tt + 2;

    STAGE(0, 0);  // prologue: tile 0 -> buffer 0 (16 gl_lds per wave)

    #pragma unroll 1
    for (int iu = 0; iu < nU; ++iu) {
      int cur = iu & 1;
      if (iu + 1 < nU) {
        STAGE(cur ^ 1, iu + 1);                       // issue next tile (async)
        asm volatile("s_waitcnt vmcnt(16)" ::: "memory");  // prev tile landed
      } else {
        asm volatile("s_waitcnt vmcnt(0)" ::: "memory");
      }
      __builtin_amdgcn_s_barrier();                   // all waves' tiles landed
      asm volatile("" ::: "memory");
      int U = iu * 64;

      #pragma unroll
      for (int hh = 0; hh < 2; ++hh) {
        // S = A @ K^T for u-half hh (32 u cols), both row-blocks
        f32x4 s[2][2] = {{{0,0,0,0},{0,0,0,0}},{{0,0,0,0},{0,0,0,0}}};
        #pragma unroll
        for (int n2 = 0; n2 < 2; ++n2) {
          int row = (hh * 2 + n2) * 16 + (lane & 15);
          #pragma unroll
          for (int ks = 0; ks < 8; ++ks) {
            int kb = ks * 4 + (lane >> 4);
            s16x8 bfr = *(const s16x8*)(&k_lds[cur][row * 256 + ((kb ^ (row & 7)) << 3)]);
            s[0][n2] = __builtin_amdgcn_mfma_f32_16x16x32_bf16(a[0][ks], bfr, s[0][n2], 0, 0, 0);
            s[1][n2] = __builtin_amdgcn_mfma_f32_16x16x32_bf16(a[1][ks], bfr, s[1][n2], 0, 0, 0);
          }
        }
        // causal mask + bf16 + write to per-wave s_lds region (swizzled)
        #pragma unroll
        for (int rb = 0; rb < 2; ++rb) {
          #pragma unroll
          for (int n2 = 0; n2 < 2; ++n2) {
            #pragma unroll
            for (int rr = 0; rr < 4; ++rr) {
              int t_loc = wid * 32 + rb * 16 + (lane >> 4) * 4 + rr;
              int u_glob = U + (hh * 2 + n2) * 16 + (lane & 15);
              float v = (u_glob <= tt * 128 + t_loc) ? s[rb][n2][rr] : 0.0f;
              int kloc = n2 * 16 + (lane & 15);
              int cb = kloc >> 3;
              s_lds[t_loc * 32 + ((cb ^ ((t_loc >> 1) & 3)) << 3) + (kloc & 7)] = f2bf(v);
            }
          }
        }
        // PV for this u-half (k=32)
        s16x8 af[2];
        #pragma unroll
        for (int rb = 0; rb < 2; ++rb) {
          int R = wid * 32 + rb * 16 + (lane & 15);
          int cb2 = (lane >> 4) ^ ((R >> 1) & 3);
          af[rb] = *(const s16x8*)(&s_lds[R * 32 + (cb2 << 3)]);
        }
        #pragma unroll
        for (int ni = 0; ni < 16; ++ni) {
          int vrow = ni * 16 + (lane & 15);
          int ub = hh * 4 + (lane >> 4);
          s16x8 bv = *(const s16x8*)(&v_lds[cur][vrow * 64 + ((ub ^ (vrow & 7)) << 3)]);
          acc[0][ni] = __builtin_amdgcn_mfma_f32_16x16x32_bf16(af[0], bv, acc[0][ni], 0, 0, 0);
          acc[1][ni] = __builtin_amdgcn_mfma_f32_16x16x32_bf16(af[1], bv, acc[1][ni], 0, 0, 0);
        }
      }
      asm volatile("s_waitcnt lgkmcnt(0)" ::: "memory");
      __builtin_amdgcn_s_barrier();   // all reads of buf[cur] done before reuse
    }

    // epilogue: head-sum via atomics
    float* ob = out + ((size_t)b * TT + tt * 128 + wid * 32) * DD;
    #pragma unroll
    for (int rb = 0; rb < 2; ++rb) {
      #pragma unroll
      for (int ni = 0; ni < 16; ++ni) {
        int col = ni * 16 + (lane & 15);
        #pragma unroll
        for (int rr = 0; rr < 4; ++rr) {
          int row = rb * 16 + (lane >> 4) * 4 + rr;
          atomicAdd(&ob[row * DD + col], acc[rb][ni][rr]);
        }
      }
    }
  }
#undef STAGE
}

// ---------------------------------------------------------------------------
extern "C" void kernel_launch(void* const* d_in, const int* in_sizes, int n_in,
                              void* d_out, int out_size, void* d_ws, size_t ws_size,
                              hipStream_t stream) {
  const float* r = (const float*)d_in[0];
  const float* Q = (const float*)d_in[1];
  const float* E = (const float*)d_in[2];
  float* out = (float*)d_out;
  char* ws = (char*)d_ws;

  size_t off = 0;
  short* rbf = (short*)(ws + off); off += (size_t)BB * TT * DD * 2;      // 4 MiB
  short* Qt  = (short*)(ws + off); off += (size_t)HH * DD * DD * 2;      // 1 MiB
  short* Ebf = (short*)(ws + off); off += (size_t)HH * DD * DD * 2;      // 1 MiB
  short* Abf = (short*)(ws + off); off += (size_t)BB * HH * TT * DD * 2; // 32 MiB
  short* Vtb = (short*)(ws + off); off += (size_t)BB * HH * DD * TT * 2; // 32 MiB

  hipMemsetAsync(d_out, 0, (size_t)out_size * sizeof(float), stream);
  cast_prep<<<1024, 256, 0, stream>>>(r, Q, E, rbf, Qt, Ebf);
  prep_gemm<<<dim3(128, HH, BB), 256, 0, stream>>>(rbf, Qt, Ebf, Abf, Vtb, 0);
  prep_gemm<<<dim3(128, HH, BB), 256, 0, stream>>>(rbf, Qt, Ebf, Abf, Vtb, 1);
  attn_main<<<dim3(256, 1, 1), 256, 0, stream>>>(Abf, rbf, Vtb, out);
}